// Round 1
// baseline (599.703 us; speedup 1.0000x reference)
//
#include <hip/hip_runtime.h>

// ---------------------------------------------------------------------------
// ExpandHarmonics: ragged expansion of reflections into Laue harmonics.
//   g      = gcd(h,k,l)
//   n_max  = floor(dHKL*g / dmin)
//   row i emits entries n = 1..n_max[i], compacted row-major.
// Outputs concatenated flat (promoted to float32):
//   [0,3M)     hkl_out   = (hkl/g)*n
//   [3M,4M)    dHKL_out  = (dHKL*g)/n
//   [4M,5M)    wl_out    = (wl*g)/n
//   [5M,37M)   meta_out  = meta[row]   (DMETA=32)
// M = out_size / 37 (harness-known total).
// ---------------------------------------------------------------------------

__device__ __forceinline__ int gcd2(int a, int b) {
    while (b) { int t = a % b; a = b; b = t; }
    return a;
}
__device__ __forceinline__ int gcd3(int a, int b, int c) {
    return gcd2(gcd2(a, b), c);
}

__device__ __forceinline__ int row_nmax(const int* __restrict__ hkl,
                                        const float* __restrict__ dHKL,
                                        float dmin, int i, int* g_out) {
    int h = hkl[3 * i], k = hkl[3 * i + 1], l = hkl[3 * i + 2];
    int g = gcd3(h, k, l);
    *g_out = g;
    float d0 = dHKL[i] * (float)g;          // same f32 op order as reference
    return (int)floorf(d0 / dmin);          // jnp.floor_divide(d0, dmin)
}

// K1: per-block sum of n_max
__global__ void k_count(const int* __restrict__ hkl, const float* __restrict__ dHKL,
                        const float* __restrict__ dmin_p,
                        int* __restrict__ bsums, int N) {
    int i = blockIdx.x * 256 + threadIdx.x;
    int nm = 0;
    if (i < N) {
        int g;
        nm = row_nmax(hkl, dHKL, dmin_p[0], i, &g);
    }
    __shared__ int red[256];
    red[threadIdx.x] = nm;
    __syncthreads();
    for (int s = 128; s > 0; s >>= 1) {
        if (threadIdx.x < s) red[threadIdx.x] += red[threadIdx.x + s];
        __syncthreads();
    }
    if (threadIdx.x == 0) bsums[blockIdx.x] = red[0];
}

// K2: exclusive scan of block sums (single block, tiled Hillis-Steele)
__global__ void k_scan(const int* __restrict__ bsums, int* __restrict__ boffs, int nb) {
    __shared__ int tmp[1024];
    __shared__ int carry;
    if (threadIdx.x == 0) carry = 0;
    __syncthreads();
    for (int t0 = 0; t0 < nb; t0 += 1024) {
        int idx = t0 + threadIdx.x;
        int v = (idx < nb) ? bsums[idx] : 0;
        tmp[threadIdx.x] = v;
        __syncthreads();
        for (int off = 1; off < 1024; off <<= 1) {
            int x = (threadIdx.x >= off) ? tmp[threadIdx.x - off] : 0;
            __syncthreads();
            tmp[threadIdx.x] += x;
            __syncthreads();
        }
        int inc = tmp[threadIdx.x];
        if (idx < nb) boffs[idx] = carry + inc - v;   // exclusive
        __syncthreads();
        if (threadIdx.x == 1023) carry += inc;        // inc of last thread == tile total
        __syncthreads();
    }
}

// K3: per-row base offset (block offset + intra-block exclusive scan),
//     emit packed (row<<8 | n) descriptor per output entry.
__global__ void k_expand(const int* __restrict__ hkl, const float* __restrict__ dHKL,
                         const float* __restrict__ dmin_p, const int* __restrict__ boffs,
                         int* __restrict__ pack, int N, int M) {
    int tid = threadIdx.x;
    int i = blockIdx.x * 256 + tid;
    int nm = 0, g;
    if (i < N) nm = row_nmax(hkl, dHKL, dmin_p[0], i, &g);
    __shared__ int tmp[256];
    tmp[tid] = nm;
    __syncthreads();
    for (int off = 1; off < 256; off <<= 1) {
        int x = (tid >= off) ? tmp[tid - off] : 0;
        __syncthreads();
        tmp[tid] += x;
        __syncthreads();
    }
    int base = boffs[blockIdx.x] + tmp[tid] - nm;
    if (i < N) {
        int p = (i << 8);
        for (int n = 1; n <= nm; n++) {
            int m = base + n - 1;
            if (m < M) pack[m] = p | n;
        }
    }
}

// K4: per-entry scalar outputs (hkl, dHKL, wavelength)
__global__ void k_scalar(const int* __restrict__ pack, const int* __restrict__ hkl,
                         const float* __restrict__ dHKL, const float* __restrict__ wl,
                         float* __restrict__ out, int M, int N) {
    int m = blockIdx.x * 256 + threadIdx.x;
    if (m >= M) return;
    int p = pack[m];
    int row = p >> 8;
    int n = p & 255;
    if (row >= N || n == 0) { row = 0; n = 1; }   // safety against poison
    int h = hkl[3 * row], k = hkl[3 * row + 1], l = hkl[3 * row + 2];
    int g = gcd3(h, k, l);
    float gf = (float)g;
    float nf = (float)n;
    out[3 * m]     = (float)((h / g) * n);
    out[3 * m + 1] = (float)((k / g) * n);
    out[3 * m + 2] = (float)((l / g) * n);
    out[(size_t)3 * M + m] = (dHKL[row] * gf) / nf;
    out[(size_t)4 * M + m] = (wl[row] * gf) / nf;
}

// K5: meta gather-scatter, one thread per output float (coalesced stores)
__global__ void k_meta(const int* __restrict__ pack, const float* __restrict__ meta,
                       float* __restrict__ out5, int total, int N) {
    int gid = blockIdx.x * 256 + threadIdx.x;
    if (gid >= total) return;
    int m = gid >> 5;           // DMETA = 32
    int c = gid & 31;
    int row = pack[m] >> 8;
    if (row >= N) row = 0;      // safety against poison
    out5[gid] = meta[(row << 5) + c];
}

extern "C" void kernel_launch(void* const* d_in, const int* in_sizes, int n_in,
                              void* d_out, int out_size, void* d_ws, size_t ws_size,
                              hipStream_t stream) {
    const int*   hkl  = (const int*)d_in[0];
    const float* dHKL = (const float*)d_in[1];
    const float* wl   = (const float*)d_in[2];
    const float* meta = (const float*)d_in[3];
    const float* dmin = (const float*)d_in[4];
    float* out = (float*)d_out;

    int N = in_sizes[0] / 3;
    int M = out_size / 37;
    int nb = (N + 255) / 256;

    int* bsums = (int*)d_ws;      // [nb]
    int* boffs = bsums + nb;      // [nb]
    int* pack  = boffs + nb;      // [M]

    k_count<<<nb, 256, 0, stream>>>(hkl, dHKL, dmin, bsums, N);
    k_scan<<<1, 1024, 0, stream>>>(bsums, boffs, nb);
    k_expand<<<nb, 256, 0, stream>>>(hkl, dHKL, dmin, boffs, pack, N, M);

    int g4 = (M + 255) / 256;
    k_scalar<<<g4, 256, 0, stream>>>(pack, hkl, dHKL, wl, out, M, N);

    int total = M * 32;
    int g5 = (total + 255) / 256;
    k_meta<<<g5, 256, 0, stream>>>(pack, meta, out + (size_t)5 * M, total, N);
}

// Round 3
// 526.673 us; speedup vs baseline: 1.1387x; 1.1387x over previous
//
#include <hip/hip_runtime.h>

// ---------------------------------------------------------------------------
// ExpandHarmonics: ragged expansion of reflections into Laue harmonics.
//   g      = gcd(h,k,l)
//   n_max  = floor(dHKL*g / dmin)
//   row i emits entries n = 1..n_max[i], compacted row-major.
// Outputs concatenated flat (promoted to float32):
//   [0,3M)     hkl_out   = (hkl/g)*n
//   [3M,4M)    dHKL_out  = (dHKL*g)/n
//   [4M,5M)    wl_out    = (wl*g)/n
//   [5M,37M)   meta_out  = meta[row]   (DMETA=32)
// M = out_size / 37 (harness-known total).
//
// R1: k_meta rewritten to float4 (16B/lane) with host-computed alignment pad
//     (meta_out base = 5M dwords, M data-dependent -> not always 16B-aligned).
//     Nontemporal stores for all large output streams.
// R2: use clang ext_vector_type for nontemporal 16B store (HIP float4 is a
//     class type the builtin rejects).
// ---------------------------------------------------------------------------

typedef float f32x4 __attribute__((ext_vector_type(4)));

__device__ __forceinline__ int gcd2(int a, int b) {
    while (b) { int t = a % b; a = b; b = t; }
    return a;
}
__device__ __forceinline__ int gcd3(int a, int b, int c) {
    return gcd2(gcd2(a, b), c);
}

__device__ __forceinline__ int row_nmax(const int* __restrict__ hkl,
                                        const float* __restrict__ dHKL,
                                        float dmin, int i, int* g_out) {
    int h = hkl[3 * i], k = hkl[3 * i + 1], l = hkl[3 * i + 2];
    int g = gcd3(h, k, l);
    *g_out = g;
    float d0 = dHKL[i] * (float)g;          // same f32 op order as reference
    return (int)floorf(d0 / dmin);          // jnp.floor_divide(d0, dmin)
}

// K1: per-block sum of n_max
__global__ void k_count(const int* __restrict__ hkl, const float* __restrict__ dHKL,
                        const float* __restrict__ dmin_p,
                        int* __restrict__ bsums, int N) {
    int i = blockIdx.x * 256 + threadIdx.x;
    int nm = 0;
    if (i < N) {
        int g;
        nm = row_nmax(hkl, dHKL, dmin_p[0], i, &g);
    }
    __shared__ int red[256];
    red[threadIdx.x] = nm;
    __syncthreads();
    for (int s = 128; s > 0; s >>= 1) {
        if (threadIdx.x < s) red[threadIdx.x] += red[threadIdx.x + s];
        __syncthreads();
    }
    if (threadIdx.x == 0) bsums[blockIdx.x] = red[0];
}

// K2: exclusive scan of block sums (single block, tiled Hillis-Steele)
__global__ void k_scan(const int* __restrict__ bsums, int* __restrict__ boffs, int nb) {
    __shared__ int tmp[1024];
    __shared__ int carry;
    if (threadIdx.x == 0) carry = 0;
    __syncthreads();
    for (int t0 = 0; t0 < nb; t0 += 1024) {
        int idx = t0 + threadIdx.x;
        int v = (idx < nb) ? bsums[idx] : 0;
        tmp[threadIdx.x] = v;
        __syncthreads();
        for (int off = 1; off < 1024; off <<= 1) {
            int x = (threadIdx.x >= off) ? tmp[threadIdx.x - off] : 0;
            __syncthreads();
            tmp[threadIdx.x] += x;
            __syncthreads();
        }
        int inc = tmp[threadIdx.x];
        if (idx < nb) boffs[idx] = carry + inc - v;   // exclusive
        __syncthreads();
        if (threadIdx.x == 1023) carry += inc;        // inc of last thread == tile total
        __syncthreads();
    }
}

// K3: per-row base offset (block offset + intra-block exclusive scan),
//     emit packed (row<<8 | n) descriptor per output entry.
__global__ void k_expand(const int* __restrict__ hkl, const float* __restrict__ dHKL,
                         const float* __restrict__ dmin_p, const int* __restrict__ boffs,
                         int* __restrict__ pack, int N, int M) {
    int tid = threadIdx.x;
    int i = blockIdx.x * 256 + tid;
    int nm = 0, g;
    if (i < N) nm = row_nmax(hkl, dHKL, dmin_p[0], i, &g);
    __shared__ int tmp[256];
    tmp[tid] = nm;
    __syncthreads();
    for (int off = 1; off < 256; off <<= 1) {
        int x = (tid >= off) ? tmp[tid - off] : 0;
        __syncthreads();
        tmp[tid] += x;
        __syncthreads();
    }
    int base = boffs[blockIdx.x] + tmp[tid] - nm;
    if (i < N) {
        int p = (i << 8);
        for (int n = 1; n <= nm; n++) {
            int m = base + n - 1;
            if (m < M) pack[m] = p | n;
        }
    }
}

// K4: per-entry scalar outputs (hkl, dHKL, wavelength)
__global__ void k_scalar(const int* __restrict__ pack, const int* __restrict__ hkl,
                         const float* __restrict__ dHKL, const float* __restrict__ wl,
                         float* __restrict__ out, int M, int N) {
    int m = blockIdx.x * 256 + threadIdx.x;
    if (m >= M) return;
    int p = pack[m];
    int row = p >> 8;
    int n = p & 255;
    if (row >= N || row < 0 || n == 0) { row = 0; n = 1; }   // safety against poison
    int h = hkl[3 * row], k = hkl[3 * row + 1], l = hkl[3 * row + 2];
    int g = gcd3(h, k, l);
    float gf = (float)g;
    float nf = (float)n;
    __builtin_nontemporal_store((float)((h / g) * n), &out[3 * m]);
    __builtin_nontemporal_store((float)((k / g) * n), &out[3 * m + 1]);
    __builtin_nontemporal_store((float)((l / g) * n), &out[3 * m + 2]);
    __builtin_nontemporal_store((dHKL[row] * gf) / nf, &out[(size_t)3 * M + m]);
    __builtin_nontemporal_store((wl[row] * gf) / nf,   &out[(size_t)4 * M + m]);
}

// K5: meta gather-scatter, one float4 (16B) per thread.
//   out5 = out + 5M (dword offset 5M may be misaligned for float4; pad realigns).
//   Body thread t handles dwords p = pad + 4t .. +3 as one aligned 16B store.
//   Extra threads (t >= nbody4) handle the <4 head dwords and <4 tail dwords.
__global__ void k_meta4(const int* __restrict__ pack, const float* __restrict__ meta,
                        float* __restrict__ out5, int total, int pad,
                        int nbody4, int nextra, int N) {
    int t = blockIdx.x * 256 + threadIdx.x;
    if (t < nbody4) {
        int p = pad + (t << 2);
        int m0 = p >> 5;
        int ra = pack[m0] >> 8;
        if (ra >= N || ra < 0) ra = 0;                 // safety against poison
        f32x4 v;
        if (pad == 0) {
            // p % 4 == 0 and rows are 32 dwords: the 4 dwords never cross a row
            const f32x4* meta4 = (const f32x4*)meta;
            v = meta4[(ra << 3) + ((p & 31) >> 2)];
        } else {
            int m3 = (p + 3) >> 5;
            int rb = (m3 == m0) ? ra : (pack[m3] >> 8);
            if (rb >= N || rb < 0) rb = 0;
            {
                int pj = p;     int mj = pj >> 5; int rj = (mj == m0) ? ra : rb;
                v.x = meta[(rj << 5) + (pj & 31)];
            }
            {
                int pj = p + 1; int mj = pj >> 5; int rj = (mj == m0) ? ra : rb;
                v.y = meta[(rj << 5) + (pj & 31)];
            }
            {
                int pj = p + 2; int mj = pj >> 5; int rj = (mj == m0) ? ra : rb;
                v.z = meta[(rj << 5) + (pj & 31)];
            }
            {
                int pj = p + 3; int mj = pj >> 5; int rj = (mj == m0) ? ra : rb;
                v.w = meta[(rj << 5) + (pj & 31)];
            }
        }
        // (5M + p) % 4 == 0 by construction of pad -> 16B-aligned store
        __builtin_nontemporal_store(v, (f32x4*)(out5 + p));
    } else {
        int e = t - nbody4;
        if (e < nextra) {
            int p = (e < pad) ? e : (pad + (nbody4 << 2) + (e - pad));
            if (p < total) {
                int m = p >> 5;
                int r = pack[m] >> 8;
                if (r >= N || r < 0) r = 0;
                __builtin_nontemporal_store(meta[(r << 5) + (p & 31)], out5 + p);
            }
        }
    }
}

extern "C" void kernel_launch(void* const* d_in, const int* in_sizes, int n_in,
                              void* d_out, int out_size, void* d_ws, size_t ws_size,
                              hipStream_t stream) {
    const int*   hkl  = (const int*)d_in[0];
    const float* dHKL = (const float*)d_in[1];
    const float* wl   = (const float*)d_in[2];
    const float* meta = (const float*)d_in[3];
    const float* dmin = (const float*)d_in[4];
    float* out = (float*)d_out;

    int N = in_sizes[0] / 3;
    int M = out_size / 37;
    int nb = (N + 255) / 256;

    int* bsums = (int*)d_ws;      // [nb]
    int* boffs = bsums + nb;      // [nb]
    int* pack  = boffs + nb;      // [M]

    k_count<<<nb, 256, 0, stream>>>(hkl, dHKL, dmin, bsums, N);
    k_scan<<<1, 1024, 0, stream>>>(bsums, boffs, nb);
    k_expand<<<nb, 256, 0, stream>>>(hkl, dHKL, dmin, boffs, pack, N, M);

    int g4 = (M + 255) / 256;
    k_scalar<<<g4, 256, 0, stream>>>(pack, hkl, dHKL, wl, out, M, N);

    // meta: float4 body + scalar head/tail, aligned via pad
    int total = 32 * M;                      // dwords of meta_out
    int base  = 5 * M;                       // dword offset of meta_out in out
    int pad   = (4 - (base & 3)) & 3;
    if (pad > total) pad = total;
    int body   = total - pad;
    int nbody4 = body >> 2;
    int tail   = body & 3;
    int nextra = pad + tail;
    int g5 = (nbody4 + nextra + 255) / 256;
    k_meta4<<<g5, 256, 0, stream>>>(pack, meta, out + (size_t)5 * M,
                                    total, pad, nbody4, nextra, N);
}